// Round 5
// baseline (272.039 us; speedup 1.0000x reference)
//
#include <hip/hip_runtime.h>

// inputs  [N=64, C=3, H=128, W=128] fp32  (12.6 MB, 16x reuse -> want L2-resident)
// samples [N=64, S=16, C=3, H=128, W=128] fp32 (201 MB, streamed once, nontemporal)
// out: scalar fp32 = sum_n min_s sum_chw (samples[n,s]-inputs[n])^2
//
// R5: pair-per-block (one fully CONTIGUOUS 192 KB NT sample stream per block,
// best DRAM page locality) + s-major block mapping b = s*64 + n. With
// round-robin block->XCD dispatch, all 16 blocks sharing inputs[n] land on
// XCD n%8 -> per-XCD input working set = 8 * 192 KB = 1.5 MB < 4 MiB L2, so
// the 16x input reuse is served by L2 instead of thrashing to L3/HBM.
// (R4's chunked variant fixed input traffic but split samples into 16
// interleaved 12 KB streams per block; R2 had contiguous streams but input
// L2 thrash. This keeps both properties. No atomics — R3 showed they cost.)
constexpr int N_BATCH = 64;
constexpr int S_SAMP  = 16;
constexpr int CHW     = 3 * 128 * 128;   // 49152 floats per (n,s) pair
constexpr int CHW4    = CHW / 4;         // 12288 float4 (= 48 * 256)

typedef float v4f __attribute__((ext_vector_type(4)));

__device__ __forceinline__ float sqdiff4(v4f s, v4f p) {
    v4f d = s - p;
    return d.x * d.x + d.y * d.y + d.z * d.z + d.w * d.w;
}

// Kernel 1: 1024 blocks x 256 threads (4 blocks/CU, all resident).
__global__ __launch_bounds__(256) void pair_sqdist_kernel(
    const float* __restrict__ inputs,
    const float* __restrict__ samples,
    float* __restrict__ ws)              // [16 s][64 n] partial losses
{
    const int b = blockIdx.x;            // s-major: b = s*64 + n
    const int n = b & 63;
    const int s = b >> 6;

    const v4f* __restrict__ inp = reinterpret_cast<const v4f*>(inputs + (size_t)n * CHW);
    const v4f* __restrict__ smp =
        reinterpret_cast<const v4f*>(samples + ((size_t)n * S_SAMP + s) * CHW);

    const int t = threadIdx.x;
    float a0 = 0.f, a1 = 0.f, a2 = 0.f, a3 = 0.f;

    int i = t;
    #pragma unroll 1
    for (int k = 0; k < 12; ++k) {
        v4f s0 = __builtin_nontemporal_load(smp + i);
        v4f s1 = __builtin_nontemporal_load(smp + i + 256);
        v4f s2 = __builtin_nontemporal_load(smp + i + 512);
        v4f s3 = __builtin_nontemporal_load(smp + i + 768);
        v4f p0 = inp[i];
        v4f p1 = inp[i + 256];
        v4f p2 = inp[i + 512];
        v4f p3 = inp[i + 768];
        a0 += sqdiff4(s0, p0);
        a1 += sqdiff4(s1, p1);
        a2 += sqdiff4(s2, p2);
        a3 += sqdiff4(s3, p3);
        i += 1024;
    }
    float acc = (a0 + a1) + (a2 + a3);

    // wave-64 butterfly reduce
    #pragma unroll
    for (int off = 32; off > 0; off >>= 1)
        acc += __shfl_down(acc, off, 64);

    __shared__ float wave_part[4];
    const int wave = t >> 6;
    if ((t & 63) == 0) wave_part[wave] = acc;
    __syncthreads();
    if (t == 0) {
        ws[b] = wave_part[0] + wave_part[1] + wave_part[2] + wave_part[3];
    }
}

// Kernel 2: one block of 64 threads. ws is [s][n]; thread n gathers its 16
// sample losses (stride 64), min, then wave-64 sum, lane 0 writes scalar.
__global__ __launch_bounds__(64) void min_sum_kernel(
    const float* __restrict__ ws,        // [16][64]
    float* __restrict__ out)
{
    const int n = threadIdx.x;           // 0..63
    float m = ws[n];
    #pragma unroll
    for (int s = 1; s < S_SAMP; ++s)
        m = fminf(m, ws[s * N_BATCH + n]);
    #pragma unroll
    for (int off = 32; off > 0; off >>= 1)
        m += __shfl_down(m, off, 64);
    if (n == 0) out[0] = m;
}

extern "C" void kernel_launch(void* const* d_in, const int* in_sizes, int n_in,
                              void* d_out, int out_size, void* d_ws, size_t ws_size,
                              hipStream_t stream) {
    const float* inputs  = (const float*)d_in[0];  // [64,3,128,128]
    const float* samples = (const float*)d_in[1];  // [64,16,3,128,128]
    float* out = (float*)d_out;                    // [1]
    float* ws  = (float*)d_ws;                     // uses 1024 floats = 4 KB

    pair_sqdist_kernel<<<N_BATCH * S_SAMP, 256, 0, stream>>>(inputs, samples, ws);
    min_sum_kernel<<<1, 64, 0, stream>>>(ws, out);
}

// Round 6
// 269.889 us; speedup vs baseline: 1.0080x; 1.0080x over previous
//
#include <hip/hip_runtime.h>

// inputs  [N=64, C=3, H=128, W=128] fp32  (12.6 MB)
// samples [N=64, S=16, C=3, H=128, W=128] fp32 (201 MB, streamed once, nontemporal)
// out: scalar fp32 = sum_n min_s sum_chw (samples[n,s]-inputs[n])^2
//
// R6 = R4 (register reuse of inputs: logical input traffic 201->12.6 MB, best
// measured at 268.6) + 2x contiguous sample segments: chunk 12->24 KB, block
// 256->512 threads. Per-thread regs unchanged (3 float4 input), waves/CU
// unchanged (2 blocks x 8 waves = 16), but each per-sample NT stream is 24 KB
// contiguous -> better DRAM page locality on the HBM-resident stream.
// History: R2 contiguous/no-reuse 277.9 | R3 +atomics/fences 320.9 (bad) |
// R4 chunked reuse 268.6 | R5 contiguous+XCD swizzle 272.0.
constexpr int N_BATCH = 64;
constexpr int S_SAMP  = 16;
constexpr int CHW     = 3 * 128 * 128;    // 49152 floats per (n,s) pair
constexpr int NCHUNK  = 8;
constexpr int CHUNK   = CHW / NCHUNK;     // 6144 floats = 24 KB contiguous
constexpr int NTHR    = 512;              // 3 float4 per thread per sample

typedef float v4f __attribute__((ext_vector_type(4)));

__device__ __forceinline__ float sqdiff4(v4f s, v4f p) {
    v4f d = s - p;
    return d.x * d.x + d.y * d.y + d.z * d.z + d.w * d.w;
}

// Kernel 1: 512 blocks (64 n x 8 chunks) x 512 threads = 2 blocks/CU, 16 waves/CU.
__global__ __launch_bounds__(NTHR) void chunk_sqdist_kernel(
    const float* __restrict__ inputs,
    const float* __restrict__ samples,
    float* __restrict__ ws)           // [64 n][8 chunk][16 s]
{
    const int b = blockIdx.x;
    const int n = b >> 3;
    const int c = b & 7;
    const int t = threadIdx.x;

    // Input chunk -> registers (read once; 12.6 MB total from HBM).
    const v4f* __restrict__ inp =
        reinterpret_cast<const v4f*>(inputs + (size_t)n * CHW + (size_t)c * CHUNK);
    const v4f p0 = inp[t];
    const v4f p1 = inp[t + NTHR];
    const v4f p2 = inp[t + 2 * NTHR];

    const float* __restrict__ smp_base =
        samples + (size_t)n * S_SAMP * CHW + (size_t)c * CHUNK;

    float acc[S_SAMP];
    #pragma unroll
    for (int s = 0; s < S_SAMP; ++s) {
        const v4f* __restrict__ sp =
            reinterpret_cast<const v4f*>(smp_base + (size_t)s * CHW);
        v4f x0 = __builtin_nontemporal_load(sp + t);
        v4f x1 = __builtin_nontemporal_load(sp + t + NTHR);
        v4f x2 = __builtin_nontemporal_load(sp + t + 2 * NTHR);
        acc[s] = sqdiff4(x0, p0) + sqdiff4(x1, p1) + sqdiff4(x2, p2);
    }

    // Block-reduce each of the 16 accumulators: wave-64 butterfly, then 8
    // wave partials per s in LDS, threads 0..15 write the block's outputs.
    __shared__ float wave_part[8][S_SAMP];
    const int wave = t >> 6;
    #pragma unroll
    for (int s = 0; s < S_SAMP; ++s) {
        float a = acc[s];
        #pragma unroll
        for (int off = 32; off > 0; off >>= 1)
            a += __shfl_down(a, off, 64);
        if ((t & 63) == 0) wave_part[wave][s] = a;
    }
    __syncthreads();
    if (t < S_SAMP) {
        float sum = 0.0f;
        #pragma unroll
        for (int w = 0; w < 8; ++w)
            sum += wave_part[w][t];
        ws[(size_t)b * S_SAMP + t] = sum;
    }
}

// Kernel 2: one block, 256 threads. pair_loss[n][s] = sum_c ws[n][c][s];
// then min over s, sum over n.
__global__ __launch_bounds__(256) void reduce_kernel(
    const float* __restrict__ ws,     // [64][8][16]
    float* __restrict__ out)
{
    __shared__ float pair[N_BATCH * S_SAMP];   // 1024 floats
    const int t = threadIdx.x;
    for (int p = t; p < N_BATCH * S_SAMP; p += 256) {
        const int n = p >> 4;
        const int s = p & 15;
        const float* base = ws + (size_t)n * NCHUNK * S_SAMP + s;
        float a = 0.0f;
        #pragma unroll
        for (int c = 0; c < NCHUNK; ++c)
            a += base[(size_t)c * S_SAMP];
        pair[p] = a;
    }
    __syncthreads();
    if (t < N_BATCH) {
        const float* pl = pair + t * S_SAMP;
        float m = pl[0];
        #pragma unroll
        for (int s = 1; s < S_SAMP; ++s)
            m = fminf(m, pl[s]);
        #pragma unroll
        for (int off = 32; off > 0; off >>= 1)
            m += __shfl_down(m, off, 64);
        if (t == 0) out[0] = m;
    }
}

extern "C" void kernel_launch(void* const* d_in, const int* in_sizes, int n_in,
                              void* d_out, int out_size, void* d_ws, size_t ws_size,
                              hipStream_t stream) {
    const float* inputs  = (const float*)d_in[0];  // [64,3,128,128]
    const float* samples = (const float*)d_in[1];  // [64,16,3,128,128]
    float* out = (float*)d_out;                    // [1]
    float* ws  = (float*)d_ws;                     // uses 8192 floats = 32 KB

    chunk_sqdist_kernel<<<N_BATCH * NCHUNK, NTHR, 0, stream>>>(inputs, samples, ws);
    reduce_kernel<<<1, 256, 0, stream>>>(ws, out);
}